// Round 18
// baseline (182.398 us; speedup 1.0000x reference)
//
#include <hip/hip_runtime.h>

// ---------------------------------------------------------------------------
// MHA with softmax over the HEADS axis (torch legacy F.softmax dim=1).
// B=2, S=2048, D=1024, H=16, dh=64. scale = sqrt(1024) = 32.
//
// Round 18: r13 base (181.5 us champion, pv=81 us x4) + ONE isolated change:
// T5 s_setprio(1) around pv's two MFMA clusters. pv is the drifting-wave
// regime (barrier-free autonomous waves) where setprio measured +4-7% on
// attn (m191); r14 bundled it with a regressing K-gather so its isolated
// sign here is unknown. Everything else byte-identical to r13.
// ws layout (56 MB): [Xb 12M ushorts | Wt 4M | Qb 4M | Kb 4M | Vt 4M]
// Zln (8M u, f16 lnZ) aliases Xb[0:8M]; Ob (4M u) aliases Xb[8M:12M].
// ---------------------------------------------------------------------------

typedef unsigned short ushort;
typedef __attribute__((ext_vector_type(8))) short short8;
typedef __attribute__((ext_vector_type(4))) short short4v;
typedef __attribute__((ext_vector_type(4))) float f32x4;
typedef __attribute__((ext_vector_type(4))) float float4v;
typedef __attribute__((ext_vector_type(4))) unsigned int uint4v;
typedef __attribute__((ext_vector_type(2))) unsigned int uint2v;

#define MFMA32(a, b, c) __builtin_amdgcn_mfma_f32_16x16x32_bf16(a, b, c, 0, 0, 0)
#define MFMA16(a, b, c) __builtin_amdgcn_mfma_f32_16x16x16bf16_1k(a, b, c, 0, 0, 0)

#define VMCNT(N) asm volatile("s_waitcnt vmcnt(" #N ")" ::: "memory")
#define SCHEDBAR() __builtin_amdgcn_sched_barrier(0)

__device__ __forceinline__ ushort f2bf(float f) {  // round-to-nearest-even
    unsigned u = __float_as_uint(f);
    u += 0x7fffu + ((u >> 16) & 1u);
    return (ushort)(u >> 16);
}
__device__ __forceinline__ ushort f2hf(float f) {  // f32 -> f16 bits (RNE)
    union { _Float16 h; ushort u; } c;
    c.h = (_Float16)f;
    return c.u;
}
__device__ __forceinline__ float hf2f(ushort h) {  // f16 bits -> f32
    union { ushort u; _Float16 h; } c;
    c.u = h;
    return (float)c.h;
}

// async global->LDS, 16B per lane. LDS dest must be wave-uniform base +
// lane*16 (linear); swizzled layouts are achieved by permuting the SOURCE.
__device__ __forceinline__ void gload16(const ushort* g, ushort* l) {
    __builtin_amdgcn_global_load_lds(
        (__attribute__((address_space(1))) void*)(unsigned long long)(g),
        (__attribute__((address_space(3))) void*)(l), 16, 0, 0);
}

// ------------------------- 1. convert inputs to bf16 -----------------------
__global__ __launch_bounds__(256) void convert_x_kernel(
    const float* __restrict__ q, const float* __restrict__ k,
    const float* __restrict__ v, ushort* __restrict__ out) {
    const size_t NPER = 4194304ull;  // 4096*1024
    size_t idx = ((size_t)blockIdx.x * 256 + threadIdx.x) * 8;
    const size_t stride = (size_t)gridDim.x * 256 * 8;
    for (; idx < 3 * NPER; idx += stride) {
        const float* src;
        size_t off;
        if (idx < NPER)          { src = q; off = idx; }
        else if (idx < 2 * NPER) { src = k; off = idx - NPER; }
        else                     { src = v; off = idx - 2 * NPER; }
        float4v a = *(const float4v*)(src + off);
        float4v b = *(const float4v*)(src + off + 4);
        union { ushort u[8]; uint4v v4; } pk;
        #pragma unroll
        for (int j = 0; j < 4; j++) { pk.u[j] = f2bf(a[j]); pk.u[4 + j] = f2bf(b[j]); }
        *(uint4v*)(out + idx) = pk.v4;
    }
}

// ------------------- 2. transpose weights: [K][N] -> [N][K] bf16 -----------
__global__ __launch_bounds__(256) void transpose_w_kernel(
    const float* __restrict__ w0, const float* __restrict__ w1,
    const float* __restrict__ w2, const float* __restrict__ w3,
    ushort* __restrict__ Wt) {
    const float* W = blockIdx.z == 0 ? w0 : blockIdx.z == 1 ? w1 : blockIdx.z == 2 ? w2 : w3;
    ushort* out = Wt + (size_t)blockIdx.z * 1024 * 1024;
    __shared__ ushort st[64 * 72];
    int t = threadIdx.x;
    int kb = blockIdx.y * 64, nb = blockIdx.x * 64;
    int c4 = (t & 15) * 4;
    int r0 = t >> 4;
    #pragma unroll
    for (int p = 0; p < 4; p++) {
        int r = r0 + p * 16;
        float4v f = *(const float4v*)(W + (size_t)(kb + r) * 1024 + nb + c4);
        union { ushort u[4]; uint2v v2; } pk;
        #pragma unroll
        for (int j = 0; j < 4; j++) pk.u[j] = f2bf(f[j]);
        *(uint2v*)(st + r * 72 + c4) = pk.v2;
    }
    __syncthreads();
    int n = t >> 2;
    int kc = (t & 3) * 16;
    union { ushort u[16]; uint4v v4[2]; } tw;
    #pragma unroll
    for (int j = 0; j < 16; j++) tw.u[j] = st[(kc + j) * 72 + n];
    uint4v* dst = (uint4v*)(out + (size_t)(nb + n) * 1024 + kb + kc);
    dst[0] = tw.v4[0];
    dst[1] = tw.v4[1];
}

// ------------------- 3./6. GEMM core: C[4096][1024] = A * Bt^T -------------
__device__ __forceinline__ void gemm_core(
    const ushort* __restrict__ A, const ushort* __restrict__ Bt,
    const float* __restrict__ bias, ushort* __restrict__ Cb,
    float* __restrict__ Cf, int mode, ushort* sA, ushort* sB) {
    int tid = threadIdx.x, lane = tid & 63, wave = tid >> 6;
    int li = lane & 15, g = lane >> 4;
    int mt = blockIdx.y * 128, nt = blockIdx.x * 128;
    int wm = (wave >> 1) * 64, wn = (wave & 1) * 64;
    f32x4 acc[4][4] = {};
    for (int k0 = 0; k0 < 1024; k0 += 64) {
        __syncthreads();
        #pragma unroll
        for (int i = 0; i < 4; i++) {
            int c = tid + i * 256;              // 16B-chunk id, 0..1023
            int row = c >> 3, chd = c & 7;
            int cg = chd ^ (row & 7);           // pre-swizzled source chunk
            gload16(A + (size_t)(mt + row) * 1024 + k0 + cg * 8, sA + c * 8);
            gload16(Bt + (size_t)(nt + row) * 1024 + k0 + cg * 8, sB + c * 8);
        }
        __syncthreads();
        #pragma unroll
        for (int kk = 0; kk < 2; kk++) {
            short8 af[4], bfr[4];
            #pragma unroll
            for (int i = 0; i < 4; i++) {
                int ra = wm + i * 16 + li;
                int cb = kk * 64 + g * 16;
                af[i] = *(const short8*)((char*)sA + ra * 128 + (cb ^ ((ra & 7) << 4)));
                int rb = wn + i * 16 + li;
                bfr[i] = *(const short8*)((char*)sB + rb * 128 + (cb ^ ((rb & 7) << 4)));
            }
            #pragma unroll
            for (int mi = 0; mi < 4; mi++)
                #pragma unroll
                for (int ni = 0; ni < 4; ni++)
                    acc[mi][ni] = MFMA32(af[mi], bfr[ni], acc[mi][ni]);
        }
    }
    #pragma unroll
    for (int mi = 0; mi < 4; mi++) {
        #pragma unroll
        for (int ni = 0; ni < 4; ni++) {
            int n = nt + wn + ni * 16 + li;
            int m0 = mt + wm + mi * 16 + g * 4;
            float bv = bias[n];
            if (mode == 0) {
                #pragma unroll
                for (int r = 0; r < 4; r++)
                    Cb[(size_t)(m0 + r) * 1024 + n] = f2bf(acc[mi][ni][r] + bv);
            } else if (mode == 1) {
                int batch = m0 >> 11, mm = m0 & 2047;
                union { ushort u[4]; uint2v v2; } pk;
                #pragma unroll
                for (int r = 0; r < 4; r++) pk.u[r] = f2bf(acc[mi][ni][r] + bv);
                *(uint2v*)(Cb + (size_t)batch * 1024 * 2048 + (size_t)n * 2048 + mm) = pk.v2;
            } else {
                #pragma unroll
                for (int r = 0; r < 4; r++)
                    Cf[(size_t)(m0 + r) * 1024 + n] = acc[mi][ni][r] + bv;
            }
        }
    }
}

__global__ __launch_bounds__(256, 3) void proj_kernel(
    const ushort* __restrict__ Xb, const ushort* __restrict__ Wt,
    const float* __restrict__ bq, const float* __restrict__ bk,
    const float* __restrict__ bv, ushort* __restrict__ Qb,
    ushort* __restrict__ Kb, ushort* __restrict__ Vtb) {
    __shared__ ushort sA[128 * 64];
    __shared__ ushort sB[128 * 64];
    int z = blockIdx.z;
    const float* bias = z == 0 ? bq : (z == 1 ? bk : bv);
    ushort* out = z == 0 ? Qb : (z == 1 ? Kb : Vtb);
    gemm_core(Xb + (size_t)z * 4194304ull, Wt + (size_t)z * 1048576ull,
              bias, out, nullptr, z == 2 ? 1 : 0, sA, sB);
}

__global__ __launch_bounds__(256, 2) void outproj_kernel(
    const ushort* __restrict__ Ob, const ushort* __restrict__ Wt3,
    const float* __restrict__ bo, float* __restrict__ out) {
    __shared__ ushort sA[128 * 64];
    __shared__ ushort sB[128 * 64];
    gemm_core(Ob, Wt3, bo, nullptr, out, 2, sA, sB);
}

// ------------------- 4. zsum: lnZ[b][q][k] = f16(ln sum_h e^(S/32)) --------
// 1024 blocks (flat, XCD-chunked), 256 thr = 4 waves. Block = 64q x 128k;
// wave owns 32k, 4 q-subtiles. Single-buffer, per-head gload_lds staging.
__global__ __launch_bounds__(256, 4) void zsum_kernel(
    const ushort* __restrict__ Qb, const ushort* __restrict__ Kb,
    ushort* __restrict__ Zln) {
    __shared__ ushort sQ[64 * 64];   // 8 KB
    __shared__ ushort sK[128 * 64];  // 16 KB
    int tid = threadIdx.x, lane = tid & 63, wid = tid >> 6;
    int li = lane & 15, g = lane >> 4;
    int bid = blockIdx.x;
    int swz = (bid & 7) * 128 + (bid >> 3);
    int qt = swz & 31, C = swz >> 5;       // C in 0..31
    int b = C >> 4, kg = C & 15;
    int q0 = qt * 64, k0 = kg * 128;
    const ushort* Qp = Qb + (size_t)(b * 2048 + q0) * 1024;
    const ushort* Kp = Kb + (size_t)(b * 2048 + k0) * 1024;
    f32x4 zacc[4][2] = {};
    for (int h = 0; h < 16; h++) {
        int co = h * 64;
        __syncthreads();
        #pragma unroll
        for (int i = 0; i < 2; i++) {   // Q: 512 chunks
            int c = tid + i * 256;
            int r = c >> 3, m = c & 7;
            gload16(Qp + (size_t)r * 1024 + co + (m ^ (r & 7)) * 8, sQ + c * 8);
        }
        #pragma unroll
        for (int i = 0; i < 4; i++) {   // K: 1024 chunks
            int c = tid + i * 256;
            int r = c >> 3, m = c & 7;
            gload16(Kp + (size_t)r * 1024 + co + (m ^ (r & 7)) * 8, sK + c * 8);
        }
        __syncthreads();
        short8 qf[4][2], kf[2][2];
        #pragma unroll
        for (int qs = 0; qs < 4; qs++)
            #pragma unroll
            for (int dc = 0; dc < 2; dc++) {
                int row = qs * 16 + li;
                qf[qs][dc] = *(const short8*)(
                    (char*)sQ + row * 128 + ((dc * 64 + g * 16) ^ ((row & 7) << 4)));
            }
        #pragma unroll
        for (int ks = 0; ks < 2; ks++)
            #pragma unroll
            for (int dc = 0; dc < 2; dc++) {
                int row = wid * 32 + ks * 16 + li;
                kf[ks][dc] = *(const short8*)(
                    (char*)sK + row * 128 + ((dc * 64 + g * 16) ^ ((row & 7) << 4)));
            }
        #pragma unroll
        for (int qs = 0; qs < 4; qs++)
            #pragma unroll
            for (int ks = 0; ks < 2; ks++) {
                f32x4 st = {0.f, 0.f, 0.f, 0.f};
                st = MFMA32(kf[ks][0], qf[qs][0], st);
                st = MFMA32(kf[ks][1], qf[qs][1], st);
                #pragma unroll
                for (int r = 0; r < 4; r++)
                    zacc[qs][ks][r] += __expf(st[r] * 0.03125f);
            }
    }
    #pragma unroll
    for (int qs = 0; qs < 4; qs++)
        #pragma unroll
        for (int ks = 0; ks < 2; ks++) {
            union { ushort u[4]; uint2v v; } pk;
            #pragma unroll
            for (int r = 0; r < 4; r++)
                pk.u[r] = f2hf(__logf(zacc[qs][ks][r]));
            *(uint2v*)(Zln + (size_t)(b * 2048 + q0 + qs * 16 + li) * 2048 +
                       k0 + wid * 32 + ks * 16 + g * 4) = pk.v;
        }
}

// ------------------- 5. pv: w = exp(st/32 - lnZ), O += w@V -----------------
// 512 blocks (XCD-chunked (qt,b), hp fastest), 256 thr = 4 waves. Wave =
// 32q x 1 head, fully autonomous: private dbuf LDS (K 4KB + V 4KB + Z 2KB
// per buf), 10 gload16/iter, vmcnt(10) counted pipeline, ZERO barriers.
// T5: setprio(1) around both MFMA clusters (drifting-wave regime).
__global__ __launch_bounds__(256, 2) void pv_kernel(
    const ushort* __restrict__ Qb, const ushort* __restrict__ Kb,
    const ushort* __restrict__ Vt, const ushort* __restrict__ Zln,
    ushort* __restrict__ Ob) {
    // per wave, per buf: [K 2048u | V 2048u | Z 1024u] = 5120 ushorts (10KB)
    __shared__ ushort S[4][2][5120];  // 80 KB total
    int tid = threadIdx.x, lane = tid & 63, wv = tid >> 6;  // wave = head
    int li = lane & 15, g = lane >> 4;
    int bid = blockIdx.x;
    int swz = (bid & 7) * 64 + (bid >> 3);
    int hp = swz & 3, p = swz >> 2;        // p in 0..127
    int b = p >> 6, qt = p & 63;
    int q0 = qt * 32;
    int head = hp * 4 + wv;
    // Q fragments in registers (one-time gather)
    short8 qf[2][2];
    #pragma unroll
    for (int qs = 0; qs < 2; qs++)
        #pragma unroll
        for (int dc = 0; dc < 2; dc++)
            qf[qs][dc] = *(const short8*)(
                Qb + (size_t)(b * 2048 + q0 + qs * 16 + li) * 1024 +
                head * 64 + dc * 32 + g * 8);
    f32x4 oacc[2][4] = {};
    // per-lane staging sources (source-swizzled, linear LDS dest)
    const ushort* Ksrc[4];
    const ushort* Vsrc[4];
    const ushort* Zsrc[2];
    #pragma unroll
    for (int i = 0; i < 4; i++) {
        int c = lane + i * 64;
        int kr = c >> 3, km = c & 7;
        Ksrc[i] = Kb + (size_t)(b * 2048 + kr) * 1024 + head * 64 + (km ^ (kr & 7)) * 8;
        int vr = c >> 2, vm = c & 3;
        Vsrc[i] = Vt + (size_t)(b * 1024 + head * 64 + vr) * 2048 + (vm ^ ((vr >> 1) & 3)) * 8;
    }
    #pragma unroll
    for (int i = 0; i < 2; i++) {
        int c = lane + i * 64;
        int zr = c >> 2, zm = c & 3;
        Zsrc[i] = Zln + (size_t)(b * 2048 + q0 + zr) * 2048 + (zm ^ ((zr >> 1) & 3)) * 8;
    }
    #define PV_STAGE(BUF, KB)                                                  \
        {                                                                      \
            ushort* dst = S[wv][BUF];                                          \
            _Pragma("unroll") for (int i = 0; i < 4; i++)                      \
                gload16(Ksrc[i] + (size_t)(KB) * 1024, dst + (lane + i * 64) * 8); \
            _Pragma("unroll") for (int i = 0; i < 4; i++)                      \
                gload16(Vsrc[i] + (KB), dst + 2048 + (lane + i * 64) * 8);     \
            _Pragma("unroll") for (int i = 0; i < 2; i++)                      \
                gload16(Zsrc[i] + (KB), dst + 4096 + (lane + i * 64) * 8);     \
        }
    PV_STAGE(0, 0)
    for (int it = 0; it < 64; ++it) {
        int cur = it & 1;
        int kb = it * 32;
        if (it + 1 < 64) {
            PV_STAGE(cur ^ 1, kb + 32)
            VMCNT(10);
        } else {
            VMCNT(0);
        }
        SCHEDBAR();
        const char* Wb = (const char*)S[wv][cur];
        // ---- QK^T ----
        short8 kf[2][2];
        #pragma unroll
        for (int ks = 0; ks < 2; ks++)
            #pragma unroll
            for (int dc = 0; dc < 2; dc++) {
                int rk = ks * 16 + li;
                kf[ks][dc] = *(const short8*)(
                    Wb + rk * 128 + ((dc * 64 + g * 16) ^ ((rk & 7) << 4)));
            }
        short4v pf[2][2];  // [qs][ks]
        f32x4 st[2][2];
        __builtin_amdgcn_s_setprio(1);
        #pragma unroll
        for (int qs = 0; qs < 2; qs++)
            #pragma unroll
            for (int ks = 0; ks < 2; ks++) {
                f32x4 t = {0.f, 0.f, 0.f, 0.f};
                t = MFMA32(kf[ks][0], qf[qs][0], t);
                t = MFMA32(kf[ks][1], qf[qs][1], t);
                st[qs][ks] = t;
            }
        __builtin_amdgcn_s_setprio(0);
        #pragma unroll
        for (int qs = 0; qs < 2; qs++)
            #pragma unroll
            for (int ks = 0; ks < 2; ks++) {
                int sl = ks * 4 + g;
                int rq = qs * 16 + li;
                union { ushort u[4]; uint2v v; } rz;
                rz.v = *(const uint2v*)(
                    Wb + 8192 + rq * 64 +
                    (((sl >> 1) ^ ((rq >> 1) & 3)) * 2 + (sl & 1)) * 8);
                float e0 = __expf(__builtin_fmaf(st[qs][ks][0], 0.03125f, -hf2f(rz.u[0])));
                float e1 = __expf(__builtin_fmaf(st[qs][ks][1], 0.03125f, -hf2f(rz.u[1])));
                float e2 = __expf(__builtin_fmaf(st[qs][ks][2], 0.03125f, -hf2f(rz.u[2])));
                float e3 = __expf(__builtin_fmaf(st[qs][ks][3], 0.03125f, -hf2f(rz.u[3])));
                unsigned a0 = __float_as_uint(e0) + 0x8000u;
                unsigned a1 = __float_as_uint(e1) + 0x8000u;
                unsigned a2 = __float_as_uint(e2) + 0x8000u;
                unsigned a3 = __float_as_uint(e3) + 0x8000u;
                union { unsigned u[2]; short4v s; } pk;
                pk.u[0] = __builtin_amdgcn_perm(a1, a0, 0x07060302u);
                pk.u[1] = __builtin_amdgcn_perm(a3, a2, 0x07060302u);
                pf[qs][ks] = pk.s;
            }
        // ---- PV ----
        __builtin_amdgcn_s_setprio(1);
        #pragma unroll
        for (int ks = 0; ks < 2; ks++) {
            int sl = ks * 4 + g;
            #pragma unroll
            for (int ds = 0; ds < 4; ds++) {
                int rv = ds * 16 + li;
                short4v vf = *(const short4v*)(
                    Wb + 4096 + rv * 64 +
                    (((sl >> 1) ^ ((rv >> 1) & 3)) * 2 + (sl & 1)) * 8);
                oacc[0][ds] = MFMA16(pf[0][ks], vf, oacc[0][ds]);
                oacc[1][ds] = MFMA16(pf[1][ks], vf, oacc[1][ds]);
            }
        }
        __builtin_amdgcn_s_setprio(0);
    }
    #undef PV_STAGE
    ushort* Oo = Ob + (size_t)(b * 2048 + q0) * 1024 + head * 64;
    #pragma unroll
    for (int qs = 0; qs < 2; qs++)
        #pragma unroll
        for (int ds = 0; ds < 4; ds++)
            #pragma unroll
            for (int r = 0; r < 4; r++)
                Oo[(size_t)(qs * 16 + g * 4 + r) * 1024 + ds * 16 + li] =
                    f2bf(oacc[qs][ds][r]);
}

// ---------------------------------------------------------------------------
extern "C" void kernel_launch(void* const* d_in, const int* in_sizes, int n_in,
                              void* d_out, int out_size, void* d_ws, size_t ws_size,
                              hipStream_t stream) {
    const float* queries = (const float*)d_in[0];
    const float* keys    = (const float*)d_in[1];
    const float* values  = (const float*)d_in[2];
    const float* Wq = (const float*)d_in[3];
    const float* bq = (const float*)d_in[4];
    const float* Wk = (const float*)d_in[5];
    const float* bk = (const float*)d_in[6];
    const float* Wv = (const float*)d_in[7];
    const float* bv = (const float*)d_in[8];
    const float* Wo = (const float*)d_in[9];
    const float* bo = (const float*)d_in[10];
    float* out = (float*)d_out;

    // ws layout (ushort units). Requires ws_size >= 56 MB.
    ushort* Xb  = (ushort*)d_ws;            // [3][4096][1024]   (12M u)
    ushort* Wt  = Xb + 12ull * 1024 * 1024; // [4][1024][1024]   (4M u)
    ushort* Qb  = Wt + 4ull * 1024 * 1024;  // [4096][1024]      (4M u)
    ushort* Kb  = Qb + 4ull * 1024 * 1024;  // [4096][1024]      (4M u)
    ushort* Vtb = Kb + 4ull * 1024 * 1024;  // [2][1024][2048]   (4M u)
    // After projections Xb is dead: Zln (8M u) and Ob (4M u) alias it.
    ushort* Zln = Xb;                        // [2][2048][2048] f16 (8M u)
    ushort* Ob  = Xb + 8ull * 1024 * 1024;   // [4096][1024]        (4M u)

    convert_x_kernel<<<2048, 256, 0, stream>>>(queries, keys, values, Xb);
    transpose_w_kernel<<<dim3(16, 16, 4), 256, 0, stream>>>(Wq, Wk, Wv, Wo, Wt);
    proj_kernel<<<dim3(8, 32, 3), 256, 0, stream>>>(Xb, Wt, bq, bk, bv, Qb, Kb, Vtb);
    zsum_kernel<<<1024, 256, 0, stream>>>(Qb, Kb, Zln);
    pv_kernel<<<512, 256, 0, stream>>>(Qb, Kb, Vtb, Zln, Ob);
    outproj_kernel<<<dim3(8, 32), 256, 0, stream>>>(Ob, Wt + 3ull * 1024 * 1024, bo, out);
}

// Round 19
// 180.180 us; speedup vs baseline: 1.0123x; 1.0123x over previous
//
#include <hip/hip_runtime.h>

// ---------------------------------------------------------------------------
// MHA with softmax over the HEADS axis (torch legacy F.softmax dim=1).
// B=2, S=2048, D=1024, H=16, dh=64. scale = sqrt(1024) = 32.
//
// Round 19: r13 champion (181.5 us; pv=81 us x5, setprio A/B null) + merge
// the two independent preprocessing kernels (convert_x 2048 blk + transpose_w
// 1024 blk) into ONE 3072-block dispatch: removes a launch gap and packs
// transpose into convert's tail. Bodies byte-identical; convert's grid-stride
// hard-pinned to its original 2048-block stride (bijective under the larger
// grid); transpose decodes its old (x,y,z) from flat bid-2048.
// ws layout (56 MB): [Xb 12M ushorts | Wt 4M | Qb 4M | Kb 4M | Vt 4M]
// Zln (8M u, f16 lnZ) aliases Xb[0:8M]; Ob (4M u) aliases Xb[8M:12M].
// ---------------------------------------------------------------------------

typedef unsigned short ushort;
typedef __attribute__((ext_vector_type(8))) short short8;
typedef __attribute__((ext_vector_type(4))) short short4v;
typedef __attribute__((ext_vector_type(4))) float f32x4;
typedef __attribute__((ext_vector_type(4))) float float4v;
typedef __attribute__((ext_vector_type(4))) unsigned int uint4v;
typedef __attribute__((ext_vector_type(2))) unsigned int uint2v;

#define MFMA32(a, b, c) __builtin_amdgcn_mfma_f32_16x16x32_bf16(a, b, c, 0, 0, 0)
#define MFMA16(a, b, c) __builtin_amdgcn_mfma_f32_16x16x16bf16_1k(a, b, c, 0, 0, 0)

#define VMCNT(N) asm volatile("s_waitcnt vmcnt(" #N ")" ::: "memory")
#define SCHEDBAR() __builtin_amdgcn_sched_barrier(0)

__device__ __forceinline__ ushort f2bf(float f) {  // round-to-nearest-even
    unsigned u = __float_as_uint(f);
    u += 0x7fffu + ((u >> 16) & 1u);
    return (ushort)(u >> 16);
}
__device__ __forceinline__ ushort f2hf(float f) {  // f32 -> f16 bits (RNE)
    union { _Float16 h; ushort u; } c;
    c.h = (_Float16)f;
    return c.u;
}
__device__ __forceinline__ float hf2f(ushort h) {  // f16 bits -> f32
    union { ushort u; _Float16 h; } c;
    c.u = h;
    return (float)c.h;
}

// async global->LDS, 16B per lane. LDS dest must be wave-uniform base +
// lane*16 (linear); swizzled layouts are achieved by permuting the SOURCE.
__device__ __forceinline__ void gload16(const ushort* g, ushort* l) {
    __builtin_amdgcn_global_load_lds(
        (__attribute__((address_space(1))) void*)(unsigned long long)(g),
        (__attribute__((address_space(3))) void*)(l), 16, 0, 0);
}

// ---------- 1.+2. fused prep: convert X (blocks 0..2047) and ---------------
// ----------        transpose weights (blocks 2048..3071)     ---------------
__global__ __launch_bounds__(256) void prep_kernel(
    const float* __restrict__ q, const float* __restrict__ k,
    const float* __restrict__ v, ushort* __restrict__ Xout,
    const float* __restrict__ w0, const float* __restrict__ w1,
    const float* __restrict__ w2, const float* __restrict__ w3,
    ushort* __restrict__ Wt) {
    __shared__ ushort st[64 * 72];
    int bid = blockIdx.x;
    if (bid < 2048) {
        // ---- convert_x body (grid-stride pinned to 2048 blocks) ----
        const size_t NPER = 4194304ull;  // 4096*1024
        size_t idx = ((size_t)bid * 256 + threadIdx.x) * 8;
        const size_t stride = 2048ull * 256 * 8;
        for (; idx < 3 * NPER; idx += stride) {
            const float* src;
            size_t off;
            if (idx < NPER)          { src = q; off = idx; }
            else if (idx < 2 * NPER) { src = k; off = idx - NPER; }
            else                     { src = v; off = idx - 2 * NPER; }
            float4v a = *(const float4v*)(src + off);
            float4v b = *(const float4v*)(src + off + 4);
            union { ushort u[8]; uint4v v4; } pk;
            #pragma unroll
            for (int j = 0; j < 4; j++) { pk.u[j] = f2bf(a[j]); pk.u[4 + j] = f2bf(b[j]); }
            *(uint4v*)(Xout + idx) = pk.v4;
        }
    } else {
        // ---- transpose_w body (decode old dim3(16,16,4) from flat id) ----
        int t6 = bid - 2048;              // 0..1023
        int bz = t6 >> 8;                 // 0..3
        int by = (t6 >> 4) & 15;          // 0..15
        int bx = t6 & 15;                 // 0..15
        const float* W = bz == 0 ? w0 : bz == 1 ? w1 : bz == 2 ? w2 : w3;
        ushort* out = Wt + (size_t)bz * 1024 * 1024;
        int t = threadIdx.x;
        int kb = by * 64, nb = bx * 64;
        int c4 = (t & 15) * 4;
        int r0 = t >> 4;
        #pragma unroll
        for (int p = 0; p < 4; p++) {
            int r = r0 + p * 16;
            float4v f = *(const float4v*)(W + (size_t)(kb + r) * 1024 + nb + c4);
            union { ushort u[4]; uint2v v2; } pk;
            #pragma unroll
            for (int j = 0; j < 4; j++) pk.u[j] = f2bf(f[j]);
            *(uint2v*)(st + r * 72 + c4) = pk.v2;
        }
        __syncthreads();
        int n = t >> 2;
        int kc = (t & 3) * 16;
        union { ushort u[16]; uint4v v4[2]; } tw;
        #pragma unroll
        for (int j = 0; j < 16; j++) tw.u[j] = st[(kc + j) * 72 + n];
        uint4v* dst = (uint4v*)(out + (size_t)(nb + n) * 1024 + kb + kc);
        dst[0] = tw.v4[0];
        dst[1] = tw.v4[1];
    }
}

// ------------------- 3./6. GEMM core: C[4096][1024] = A * Bt^T -------------
__device__ __forceinline__ void gemm_core(
    const ushort* __restrict__ A, const ushort* __restrict__ Bt,
    const float* __restrict__ bias, ushort* __restrict__ Cb,
    float* __restrict__ Cf, int mode, ushort* sA, ushort* sB) {
    int tid = threadIdx.x, lane = tid & 63, wave = tid >> 6;
    int li = lane & 15, g = lane >> 4;
    int mt = blockIdx.y * 128, nt = blockIdx.x * 128;
    int wm = (wave >> 1) * 64, wn = (wave & 1) * 64;
    f32x4 acc[4][4] = {};
    for (int k0 = 0; k0 < 1024; k0 += 64) {
        __syncthreads();
        #pragma unroll
        for (int i = 0; i < 4; i++) {
            int c = tid + i * 256;              // 16B-chunk id, 0..1023
            int row = c >> 3, chd = c & 7;
            int cg = chd ^ (row & 7);           // pre-swizzled source chunk
            gload16(A + (size_t)(mt + row) * 1024 + k0 + cg * 8, sA + c * 8);
            gload16(Bt + (size_t)(nt + row) * 1024 + k0 + cg * 8, sB + c * 8);
        }
        __syncthreads();
        #pragma unroll
        for (int kk = 0; kk < 2; kk++) {
            short8 af[4], bfr[4];
            #pragma unroll
            for (int i = 0; i < 4; i++) {
                int ra = wm + i * 16 + li;
                int cb = kk * 64 + g * 16;
                af[i] = *(const short8*)((char*)sA + ra * 128 + (cb ^ ((ra & 7) << 4)));
                int rb = wn + i * 16 + li;
                bfr[i] = *(const short8*)((char*)sB + rb * 128 + (cb ^ ((rb & 7) << 4)));
            }
            #pragma unroll
            for (int mi = 0; mi < 4; mi++)
                #pragma unroll
                for (int ni = 0; ni < 4; ni++)
                    acc[mi][ni] = MFMA32(af[mi], bfr[ni], acc[mi][ni]);
        }
    }
    #pragma unroll
    for (int mi = 0; mi < 4; mi++) {
        #pragma unroll
        for (int ni = 0; ni < 4; ni++) {
            int n = nt + wn + ni * 16 + li;
            int m0 = mt + wm + mi * 16 + g * 4;
            float bv = bias[n];
            if (mode == 0) {
                #pragma unroll
                for (int r = 0; r < 4; r++)
                    Cb[(size_t)(m0 + r) * 1024 + n] = f2bf(acc[mi][ni][r] + bv);
            } else if (mode == 1) {
                int batch = m0 >> 11, mm = m0 & 2047;
                union { ushort u[4]; uint2v v2; } pk;
                #pragma unroll
                for (int r = 0; r < 4; r++) pk.u[r] = f2bf(acc[mi][ni][r] + bv);
                *(uint2v*)(Cb + (size_t)batch * 1024 * 2048 + (size_t)n * 2048 + mm) = pk.v2;
            } else {
                #pragma unroll
                for (int r = 0; r < 4; r++)
                    Cf[(size_t)(m0 + r) * 1024 + n] = acc[mi][ni][r] + bv;
            }
        }
    }
}

__global__ __launch_bounds__(256, 3) void proj_kernel(
    const ushort* __restrict__ Xb, const ushort* __restrict__ Wt,
    const float* __restrict__ bq, const float* __restrict__ bk,
    const float* __restrict__ bv, ushort* __restrict__ Qb,
    ushort* __restrict__ Kb, ushort* __restrict__ Vtb) {
    __shared__ ushort sA[128 * 64];
    __shared__ ushort sB[128 * 64];
    int z = blockIdx.z;
    const float* bias = z == 0 ? bq : (z == 1 ? bk : bv);
    ushort* out = z == 0 ? Qb : (z == 1 ? Kb : Vtb);
    gemm_core(Xb + (size_t)z * 4194304ull, Wt + (size_t)z * 1048576ull,
              bias, out, nullptr, z == 2 ? 1 : 0, sA, sB);
}

__global__ __launch_bounds__(256, 2) void outproj_kernel(
    const ushort* __restrict__ Ob, const ushort* __restrict__ Wt3,
    const float* __restrict__ bo, float* __restrict__ out) {
    __shared__ ushort sA[128 * 64];
    __shared__ ushort sB[128 * 64];
    gemm_core(Ob, Wt3, bo, nullptr, out, 2, sA, sB);
}

// ------------------- 4. zsum: lnZ[b][q][k] = f16(ln sum_h e^(S/32)) --------
// 1024 blocks (flat, XCD-chunked), 256 thr = 4 waves. Block = 64q x 128k;
// wave owns 32k, 4 q-subtiles. Single-buffer, per-head gload_lds staging.
__global__ __launch_bounds__(256, 4) void zsum_kernel(
    const ushort* __restrict__ Qb, const ushort* __restrict__ Kb,
    ushort* __restrict__ Zln) {
    __shared__ ushort sQ[64 * 64];   // 8 KB
    __shared__ ushort sK[128 * 64];  // 16 KB
    int tid = threadIdx.x, lane = tid & 63, wid = tid >> 6;
    int li = lane & 15, g = lane >> 4;
    int bid = blockIdx.x;
    int swz = (bid & 7) * 128 + (bid >> 3);
    int qt = swz & 31, C = swz >> 5;       // C in 0..31
    int b = C >> 4, kg = C & 15;
    int q0 = qt * 64, k0 = kg * 128;
    const ushort* Qp = Qb + (size_t)(b * 2048 + q0) * 1024;
    const ushort* Kp = Kb + (size_t)(b * 2048 + k0) * 1024;
    f32x4 zacc[4][2] = {};
    for (int h = 0; h < 16; h++) {
        int co = h * 64;
        __syncthreads();
        #pragma unroll
        for (int i = 0; i < 2; i++) {   // Q: 512 chunks
            int c = tid + i * 256;
            int r = c >> 3, m = c & 7;
            gload16(Qp + (size_t)r * 1024 + co + (m ^ (r & 7)) * 8, sQ + c * 8);
        }
        #pragma unroll
        for (int i = 0; i < 4; i++) {   // K: 1024 chunks
            int c = tid + i * 256;
            int r = c >> 3, m = c & 7;
            gload16(Kp + (size_t)r * 1024 + co + (m ^ (r & 7)) * 8, sK + c * 8);
        }
        __syncthreads();
        short8 qf[4][2], kf[2][2];
        #pragma unroll
        for (int qs = 0; qs < 4; qs++)
            #pragma unroll
            for (int dc = 0; dc < 2; dc++) {
                int row = qs * 16 + li;
                qf[qs][dc] = *(const short8*)(
                    (char*)sQ + row * 128 + ((dc * 64 + g * 16) ^ ((row & 7) << 4)));
            }
        #pragma unroll
        for (int ks = 0; ks < 2; ks++)
            #pragma unroll
            for (int dc = 0; dc < 2; dc++) {
                int row = wid * 32 + ks * 16 + li;
                kf[ks][dc] = *(const short8*)(
                    (char*)sK + row * 128 + ((dc * 64 + g * 16) ^ ((row & 7) << 4)));
            }
        #pragma unroll
        for (int qs = 0; qs < 4; qs++)
            #pragma unroll
            for (int ks = 0; ks < 2; ks++) {
                f32x4 st = {0.f, 0.f, 0.f, 0.f};
                st = MFMA32(kf[ks][0], qf[qs][0], st);
                st = MFMA32(kf[ks][1], qf[qs][1], st);
                #pragma unroll
                for (int r = 0; r < 4; r++)
                    zacc[qs][ks][r] += __expf(st[r] * 0.03125f);
            }
    }
    #pragma unroll
    for (int qs = 0; qs < 4; qs++)
        #pragma unroll
        for (int ks = 0; ks < 2; ks++) {
            union { ushort u[4]; uint2v v; } pk;
            #pragma unroll
            for (int r = 0; r < 4; r++)
                pk.u[r] = f2hf(__logf(zacc[qs][ks][r]));
            *(uint2v*)(Zln + (size_t)(b * 2048 + q0 + qs * 16 + li) * 2048 +
                       k0 + wid * 32 + ks * 16 + g * 4) = pk.v;
        }
}

// ------------------- 5. pv: w = exp(st/32 - lnZ), O += w@V -----------------
// 512 blocks (XCD-chunked (qt,b), hp fastest), 256 thr = 4 waves. Wave =
// 32q x 1 head, fully autonomous: private dbuf LDS (K 4KB + V 4KB + Z 2KB
// per buf), 10 gload16/iter, vmcnt(10) counted pipeline, ZERO barriers.
__global__ __launch_bounds__(256, 2) void pv_kernel(
    const ushort* __restrict__ Qb, const ushort* __restrict__ Kb,
    const ushort* __restrict__ Vt, const ushort* __restrict__ Zln,
    ushort* __restrict__ Ob) {
    // per wave, per buf: [K 2048u | V 2048u | Z 1024u] = 5120 ushorts (10KB)
    __shared__ ushort S[4][2][5120];  // 80 KB total
    int tid = threadIdx.x, lane = tid & 63, wv = tid >> 6;  // wave = head
    int li = lane & 15, g = lane >> 4;
    int bid = blockIdx.x;
    int swz = (bid & 7) * 64 + (bid >> 3);
    int hp = swz & 3, p = swz >> 2;        // p in 0..127
    int b = p >> 6, qt = p & 63;
    int q0 = qt * 32;
    int head = hp * 4 + wv;
    // Q fragments in registers (one-time gather)
    short8 qf[2][2];
    #pragma unroll
    for (int qs = 0; qs < 2; qs++)
        #pragma unroll
        for (int dc = 0; dc < 2; dc++)
            qf[qs][dc] = *(const short8*)(
                Qb + (size_t)(b * 2048 + q0 + qs * 16 + li) * 1024 +
                head * 64 + dc * 32 + g * 8);
    f32x4 oacc[2][4] = {};
    // per-lane staging sources (source-swizzled, linear LDS dest)
    const ushort* Ksrc[4];
    const ushort* Vsrc[4];
    const ushort* Zsrc[2];
    #pragma unroll
    for (int i = 0; i < 4; i++) {
        int c = lane + i * 64;
        int kr = c >> 3, km = c & 7;
        Ksrc[i] = Kb + (size_t)(b * 2048 + kr) * 1024 + head * 64 + (km ^ (kr & 7)) * 8;
        int vr = c >> 2, vm = c & 3;
        Vsrc[i] = Vt + (size_t)(b * 1024 + head * 64 + vr) * 2048 + (vm ^ ((vr >> 1) & 3)) * 8;
    }
    #pragma unroll
    for (int i = 0; i < 2; i++) {
        int c = lane + i * 64;
        int zr = c >> 2, zm = c & 3;
        Zsrc[i] = Zln + (size_t)(b * 2048 + q0 + zr) * 2048 + (zm ^ ((zr >> 1) & 3)) * 8;
    }
    #define PV_STAGE(BUF, KB)                                                  \
        {                                                                      \
            ushort* dst = S[wv][BUF];                                          \
            _Pragma("unroll") for (int i = 0; i < 4; i++)                      \
                gload16(Ksrc[i] + (size_t)(KB) * 1024, dst + (lane + i * 64) * 8); \
            _Pragma("unroll") for (int i = 0; i < 4; i++)                      \
                gload16(Vsrc[i] + (KB), dst + 2048 + (lane + i * 64) * 8);     \
            _Pragma("unroll") for (int i = 0; i < 2; i++)                      \
                gload16(Zsrc[i] + (KB), dst + 4096 + (lane + i * 64) * 8);     \
        }
    PV_STAGE(0, 0)
    for (int it = 0; it < 64; ++it) {
        int cur = it & 1;
        int kb = it * 32;
        if (it + 1 < 64) {
            PV_STAGE(cur ^ 1, kb + 32)
            VMCNT(10);
        } else {
            VMCNT(0);
        }
        SCHEDBAR();
        const char* Wb = (const char*)S[wv][cur];
        // ---- QK^T ----
        short8 kf[2][2];
        #pragma unroll
        for (int ks = 0; ks < 2; ks++)
            #pragma unroll
            for (int dc = 0; dc < 2; dc++) {
                int rk = ks * 16 + li;
                kf[ks][dc] = *(const short8*)(
                    Wb + rk * 128 + ((dc * 64 + g * 16) ^ ((rk & 7) << 4)));
            }
        short4v pf[2][2];  // [qs][ks]
        #pragma unroll
        for (int qs = 0; qs < 2; qs++)
            #pragma unroll
            for (int ks = 0; ks < 2; ks++) {
                f32x4 st = {0.f, 0.f, 0.f, 0.f};
                st = MFMA32(kf[ks][0], qf[qs][0], st);
                st = MFMA32(kf[ks][1], qf[qs][1], st);
                int sl = ks * 4 + g;
                int rq = qs * 16 + li;
                union { ushort u[4]; uint2v v; } rz;
                rz.v = *(const uint2v*)(
                    Wb + 8192 + rq * 64 +
                    (((sl >> 1) ^ ((rq >> 1) & 3)) * 2 + (sl & 1)) * 8);
                float e0 = __expf(__builtin_fmaf(st[0], 0.03125f, -hf2f(rz.u[0])));
                float e1 = __expf(__builtin_fmaf(st[1], 0.03125f, -hf2f(rz.u[1])));
                float e2 = __expf(__builtin_fmaf(st[2], 0.03125f, -hf2f(rz.u[2])));
                float e3 = __expf(__builtin_fmaf(st[3], 0.03125f, -hf2f(rz.u[3])));
                unsigned a0 = __float_as_uint(e0) + 0x8000u;
                unsigned a1 = __float_as_uint(e1) + 0x8000u;
                unsigned a2 = __float_as_uint(e2) + 0x8000u;
                unsigned a3 = __float_as_uint(e3) + 0x8000u;
                union { unsigned u[2]; short4v s; } pk;
                pk.u[0] = __builtin_amdgcn_perm(a1, a0, 0x07060302u);
                pk.u[1] = __builtin_amdgcn_perm(a3, a2, 0x07060302u);
                pf[qs][ks] = pk.s;
            }
        // ---- PV ----
        #pragma unroll
        for (int ks = 0; ks < 2; ks++) {
            int sl = ks * 4 + g;
            #pragma unroll
            for (int ds = 0; ds < 4; ds++) {
                int rv = ds * 16 + li;
                short4v vf = *(const short4v*)(
                    Wb + 4096 + rv * 64 +
                    (((sl >> 1) ^ ((rv >> 1) & 3)) * 2 + (sl & 1)) * 8);
                oacc[0][ds] = MFMA16(pf[0][ks], vf, oacc[0][ds]);
                oacc[1][ds] = MFMA16(pf[1][ks], vf, oacc[1][ds]);
            }
        }
    }
    #undef PV_STAGE
    ushort* Oo = Ob + (size_t)(b * 2048 + q0) * 1024 + head * 64;
    #pragma unroll
    for (int qs = 0; qs < 2; qs++)
        #pragma unroll
        for (int ds = 0; ds < 4; ds++)
            #pragma unroll
            for (int r = 0; r < 4; r++)
                Oo[(size_t)(qs * 16 + g * 4 + r) * 1024 + ds * 16 + li] =
                    f2bf(oacc[qs][ds][r]);
}

// ---------------------------------------------------------------------------
extern "C" void kernel_launch(void* const* d_in, const int* in_sizes, int n_in,
                              void* d_out, int out_size, void* d_ws, size_t ws_size,
                              hipStream_t stream) {
    const float* queries = (const float*)d_in[0];
    const float* keys    = (const float*)d_in[1];
    const float* values  = (const float*)d_in[2];
    const float* Wq = (const float*)d_in[3];
    const float* bq = (const float*)d_in[4];
    const float* Wk = (const float*)d_in[5];
    const float* bk = (const float*)d_in[6];
    const float* Wv = (const float*)d_in[7];
    const float* bv = (const float*)d_in[8];
    const float* Wo = (const float*)d_in[9];
    const float* bo = (const float*)d_in[10];
    float* out = (float*)d_out;

    // ws layout (ushort units). Requires ws_size >= 56 MB.
    ushort* Xb  = (ushort*)d_ws;            // [3][4096][1024]   (12M u)
    ushort* Wt  = Xb + 12ull * 1024 * 1024; // [4][1024][1024]   (4M u)
    ushort* Qb  = Wt + 4ull * 1024 * 1024;  // [4096][1024]      (4M u)
    ushort* Kb  = Qb + 4ull * 1024 * 1024;  // [4096][1024]      (4M u)
    ushort* Vtb = Kb + 4ull * 1024 * 1024;  // [2][1024][2048]   (4M u)
    // After projections Xb is dead: Zln (8M u) and Ob (4M u) alias it.
    ushort* Zln = Xb;                        // [2][2048][2048] f16 (8M u)
    ushort* Ob  = Xb + 8ull * 1024 * 1024;   // [4096][1024]        (4M u)

    prep_kernel<<<3072, 256, 0, stream>>>(queries, keys, values, Xb,
                                          Wq, Wk, Wv, Wo, Wt);
    proj_kernel<<<dim3(8, 32, 3), 256, 0, stream>>>(Xb, Wt, bq, bk, bv, Qb, Kb, Vtb);
    zsum_kernel<<<1024, 256, 0, stream>>>(Qb, Kb, Zln);
    pv_kernel<<<512, 256, 0, stream>>>(Qb, Kb, Vtb, Zln, Ob);
    outproj_kernel<<<dim3(8, 32), 256, 0, stream>>>(Ob, Wt + 3ull * 1024 * 1024, bo, out);
}

// Round 20
// 179.921 us; speedup vs baseline: 1.0138x; 1.0014x over previous
//
#include <hip/hip_runtime.h>

// ---------------------------------------------------------------------------
// MHA with softmax over the HEADS axis (torch legacy F.softmax dim=1).
// B=2, S=2048, D=1024, H=16, dh=64. scale = sqrt(1024) = 32.
//
// FINAL (round 20 = round 19 champion, 180.2 us; converged):
//  prep    : fused convert-X + weight-transpose (3072 blocks, one dispatch)
//  proj    : fused Q/K/V^T projection GEMMs (gload_lds + XOR-swizzle LDS)
//  zsum    : lnZ[b][q][k] = f16(ln sum_h exp(S/32)) — head-softmax denom
//  pv      : barrier-free wave-autonomous attention: wave = 32q x 1 head,
//            private dbuf LDS, 10 gload16/iter, counted vmcnt(10), w =
//            exp(st/32 - lnZ) via single-TRANS __expf + v_perm bf16 pack
//  outproj : out = Ob @ Wo + bo (f32)
// Ledger: k-split +48, K-to-reg +19, gemm-dbuf/exp2f +20, V-to-reg +67,
// lockstep +37, setprio null, launch-bounds null. pv latency-bound at the
// 2-waves/SIMD LDS cap; all escape routes measured regressive.
// ws layout (56 MB): [Xb 12M ushorts | Wt 4M | Qb 4M | Kb 4M | Vt 4M]
// Zln (8M u, f16 lnZ) aliases Xb[0:8M]; Ob (4M u) aliases Xb[8M:12M].
// ---------------------------------------------------------------------------

typedef unsigned short ushort;
typedef __attribute__((ext_vector_type(8))) short short8;
typedef __attribute__((ext_vector_type(4))) short short4v;
typedef __attribute__((ext_vector_type(4))) float f32x4;
typedef __attribute__((ext_vector_type(4))) float float4v;
typedef __attribute__((ext_vector_type(4))) unsigned int uint4v;
typedef __attribute__((ext_vector_type(2))) unsigned int uint2v;

#define MFMA32(a, b, c) __builtin_amdgcn_mfma_f32_16x16x32_bf16(a, b, c, 0, 0, 0)
#define MFMA16(a, b, c) __builtin_amdgcn_mfma_f32_16x16x16bf16_1k(a, b, c, 0, 0, 0)

#define VMCNT(N) asm volatile("s_waitcnt vmcnt(" #N ")" ::: "memory")
#define SCHEDBAR() __builtin_amdgcn_sched_barrier(0)

__device__ __forceinline__ ushort f2bf(float f) {  // round-to-nearest-even
    unsigned u = __float_as_uint(f);
    u += 0x7fffu + ((u >> 16) & 1u);
    return (ushort)(u >> 16);
}
__device__ __forceinline__ ushort f2hf(float f) {  // f32 -> f16 bits (RNE)
    union { _Float16 h; ushort u; } c;
    c.h = (_Float16)f;
    return c.u;
}
__device__ __forceinline__ float hf2f(ushort h) {  // f16 bits -> f32
    union { ushort u; _Float16 h; } c;
    c.u = h;
    return (float)c.h;
}

// async global->LDS, 16B per lane. LDS dest must be wave-uniform base +
// lane*16 (linear); swizzled layouts are achieved by permuting the SOURCE.
__device__ __forceinline__ void gload16(const ushort* g, ushort* l) {
    __builtin_amdgcn_global_load_lds(
        (__attribute__((address_space(1))) void*)(unsigned long long)(g),
        (__attribute__((address_space(3))) void*)(l), 16, 0, 0);
}

// ---------- 1.+2. fused prep: convert X (blocks 0..2047) and ---------------
// ----------        transpose weights (blocks 2048..3071)     ---------------
__global__ __launch_bounds__(256) void prep_kernel(
    const float* __restrict__ q, const float* __restrict__ k,
    const float* __restrict__ v, ushort* __restrict__ Xout,
    const float* __restrict__ w0, const float* __restrict__ w1,
    const float* __restrict__ w2, const float* __restrict__ w3,
    ushort* __restrict__ Wt) {
    __shared__ ushort st[64 * 72];
    int bid = blockIdx.x;
    if (bid < 2048) {
        // ---- convert_x body (grid-stride pinned to 2048 blocks) ----
        const size_t NPER = 4194304ull;  // 4096*1024
        size_t idx = ((size_t)bid * 256 + threadIdx.x) * 8;
        const size_t stride = 2048ull * 256 * 8;
        for (; idx < 3 * NPER; idx += stride) {
            const float* src;
            size_t off;
            if (idx < NPER)          { src = q; off = idx; }
            else if (idx < 2 * NPER) { src = k; off = idx - NPER; }
            else                     { src = v; off = idx - 2 * NPER; }
            float4v a = *(const float4v*)(src + off);
            float4v b = *(const float4v*)(src + off + 4);
            union { ushort u[8]; uint4v v4; } pk;
            #pragma unroll
            for (int j = 0; j < 4; j++) { pk.u[j] = f2bf(a[j]); pk.u[4 + j] = f2bf(b[j]); }
            *(uint4v*)(Xout + idx) = pk.v4;
        }
    } else {
        // ---- transpose_w body (decode old dim3(16,16,4) from flat id) ----
        int t6 = bid - 2048;              // 0..1023
        int bz = t6 >> 8;                 // 0..3
        int by = (t6 >> 4) & 15;          // 0..15
        int bx = t6 & 15;                 // 0..15
        const float* W = bz == 0 ? w0 : bz == 1 ? w1 : bz == 2 ? w2 : w3;
        ushort* out = Wt + (size_t)bz * 1024 * 1024;
        int t = threadIdx.x;
        int kb = by * 64, nb = bx * 64;
        int c4 = (t & 15) * 4;
        int r0 = t >> 4;
        #pragma unroll
        for (int p = 0; p < 4; p++) {
            int r = r0 + p * 16;
            float4v f = *(const float4v*)(W + (size_t)(kb + r) * 1024 + nb + c4);
            union { ushort u[4]; uint2v v2; } pk;
            #pragma unroll
            for (int j = 0; j < 4; j++) pk.u[j] = f2bf(f[j]);
            *(uint2v*)(st + r * 72 + c4) = pk.v2;
        }
        __syncthreads();
        int n = t >> 2;
        int kc = (t & 3) * 16;
        union { ushort u[16]; uint4v v4[2]; } tw;
        #pragma unroll
        for (int j = 0; j < 16; j++) tw.u[j] = st[(kc + j) * 72 + n];
        uint4v* dst = (uint4v*)(out + (size_t)(nb + n) * 1024 + kb + kc);
        dst[0] = tw.v4[0];
        dst[1] = tw.v4[1];
    }
}

// ------------------- 3./6. GEMM core: C[4096][1024] = A * Bt^T -------------
__device__ __forceinline__ void gemm_core(
    const ushort* __restrict__ A, const ushort* __restrict__ Bt,
    const float* __restrict__ bias, ushort* __restrict__ Cb,
    float* __restrict__ Cf, int mode, ushort* sA, ushort* sB) {
    int tid = threadIdx.x, lane = tid & 63, wave = tid >> 6;
    int li = lane & 15, g = lane >> 4;
    int mt = blockIdx.y * 128, nt = blockIdx.x * 128;
    int wm = (wave >> 1) * 64, wn = (wave & 1) * 64;
    f32x4 acc[4][4] = {};
    for (int k0 = 0; k0 < 1024; k0 += 64) {
        __syncthreads();
        #pragma unroll
        for (int i = 0; i < 4; i++) {
            int c = tid + i * 256;              // 16B-chunk id, 0..1023
            int row = c >> 3, chd = c & 7;
            int cg = chd ^ (row & 7);           // pre-swizzled source chunk
            gload16(A + (size_t)(mt + row) * 1024 + k0 + cg * 8, sA + c * 8);
            gload16(Bt + (size_t)(nt + row) * 1024 + k0 + cg * 8, sB + c * 8);
        }
        __syncthreads();
        #pragma unroll
        for (int kk = 0; kk < 2; kk++) {
            short8 af[4], bfr[4];
            #pragma unroll
            for (int i = 0; i < 4; i++) {
                int ra = wm + i * 16 + li;
                int cb = kk * 64 + g * 16;
                af[i] = *(const short8*)((char*)sA + ra * 128 + (cb ^ ((ra & 7) << 4)));
                int rb = wn + i * 16 + li;
                bfr[i] = *(const short8*)((char*)sB + rb * 128 + (cb ^ ((rb & 7) << 4)));
            }
            #pragma unroll
            for (int mi = 0; mi < 4; mi++)
                #pragma unroll
                for (int ni = 0; ni < 4; ni++)
                    acc[mi][ni] = MFMA32(af[mi], bfr[ni], acc[mi][ni]);
        }
    }
    #pragma unroll
    for (int mi = 0; mi < 4; mi++) {
        #pragma unroll
        for (int ni = 0; ni < 4; ni++) {
            int n = nt + wn + ni * 16 + li;
            int m0 = mt + wm + mi * 16 + g * 4;
            float bv = bias[n];
            if (mode == 0) {
                #pragma unroll
                for (int r = 0; r < 4; r++)
                    Cb[(size_t)(m0 + r) * 1024 + n] = f2bf(acc[mi][ni][r] + bv);
            } else if (mode == 1) {
                int batch = m0 >> 11, mm = m0 & 2047;
                union { ushort u[4]; uint2v v2; } pk;
                #pragma unroll
                for (int r = 0; r < 4; r++) pk.u[r] = f2bf(acc[mi][ni][r] + bv);
                *(uint2v*)(Cb + (size_t)batch * 1024 * 2048 + (size_t)n * 2048 + mm) = pk.v2;
            } else {
                #pragma unroll
                for (int r = 0; r < 4; r++)
                    Cf[(size_t)(m0 + r) * 1024 + n] = acc[mi][ni][r] + bv;
            }
        }
    }
}

__global__ __launch_bounds__(256, 3) void proj_kernel(
    const ushort* __restrict__ Xb, const ushort* __restrict__ Wt,
    const float* __restrict__ bq, const float* __restrict__ bk,
    const float* __restrict__ bv, ushort* __restrict__ Qb,
    ushort* __restrict__ Kb, ushort* __restrict__ Vtb) {
    __shared__ ushort sA[128 * 64];
    __shared__ ushort sB[128 * 64];
    int z = blockIdx.z;
    const float* bias = z == 0 ? bq : (z == 1 ? bk : bv);
    ushort* out = z == 0 ? Qb : (z == 1 ? Kb : Vtb);
    gemm_core(Xb + (size_t)z * 4194304ull, Wt + (size_t)z * 1048576ull,
              bias, out, nullptr, z == 2 ? 1 : 0, sA, sB);
}

__global__ __launch_bounds__(256, 2) void outproj_kernel(
    const ushort* __restrict__ Ob, const ushort* __restrict__ Wt3,
    const float* __restrict__ bo, float* __restrict__ out) {
    __shared__ ushort sA[128 * 64];
    __shared__ ushort sB[128 * 64];
    gemm_core(Ob, Wt3, bo, nullptr, out, 2, sA, sB);
}

// ------------------- 4. zsum: lnZ[b][q][k] = f16(ln sum_h e^(S/32)) --------
// 1024 blocks (flat, XCD-chunked), 256 thr = 4 waves. Block = 64q x 128k;
// wave owns 32k, 4 q-subtiles. Single-buffer, per-head gload_lds staging.
__global__ __launch_bounds__(256, 4) void zsum_kernel(
    const ushort* __restrict__ Qb, const ushort* __restrict__ Kb,
    ushort* __restrict__ Zln) {
    __shared__ ushort sQ[64 * 64];   // 8 KB
    __shared__ ushort sK[128 * 64];  // 16 KB
    int tid = threadIdx.x, lane = tid & 63, wid = tid >> 6;
    int li = lane & 15, g = lane >> 4;
    int bid = blockIdx.x;
    int swz = (bid & 7) * 128 + (bid >> 3);
    int qt = swz & 31, C = swz >> 5;       // C in 0..31
    int b = C >> 4, kg = C & 15;
    int q0 = qt * 64, k0 = kg * 128;
    const ushort* Qp = Qb + (size_t)(b * 2048 + q0) * 1024;
    const ushort* Kp = Kb + (size_t)(b * 2048 + k0) * 1024;
    f32x4 zacc[4][2] = {};
    for (int h = 0; h < 16; h++) {
        int co = h * 64;
        __syncthreads();
        #pragma unroll
        for (int i = 0; i < 2; i++) {   // Q: 512 chunks
            int c = tid + i * 256;
            int r = c >> 3, m = c & 7;
            gload16(Qp + (size_t)r * 1024 + co + (m ^ (r & 7)) * 8, sQ + c * 8);
        }
        #pragma unroll
        for (int i = 0; i < 4; i++) {   // K: 1024 chunks
            int c = tid + i * 256;
            int r = c >> 3, m = c & 7;
            gload16(Kp + (size_t)r * 1024 + co + (m ^ (r & 7)) * 8, sK + c * 8);
        }
        __syncthreads();
        short8 qf[4][2], kf[2][2];
        #pragma unroll
        for (int qs = 0; qs < 4; qs++)
            #pragma unroll
            for (int dc = 0; dc < 2; dc++) {
                int row = qs * 16 + li;
                qf[qs][dc] = *(const short8*)(
                    (char*)sQ + row * 128 + ((dc * 64 + g * 16) ^ ((row & 7) << 4)));
            }
        #pragma unroll
        for (int ks = 0; ks < 2; ks++)
            #pragma unroll
            for (int dc = 0; dc < 2; dc++) {
                int row = wid * 32 + ks * 16 + li;
                kf[ks][dc] = *(const short8*)(
                    (char*)sK + row * 128 + ((dc * 64 + g * 16) ^ ((row & 7) << 4)));
            }
        #pragma unroll
        for (int qs = 0; qs < 4; qs++)
            #pragma unroll
            for (int ks = 0; ks < 2; ks++) {
                f32x4 st = {0.f, 0.f, 0.f, 0.f};
                st = MFMA32(kf[ks][0], qf[qs][0], st);
                st = MFMA32(kf[ks][1], qf[qs][1], st);
                #pragma unroll
                for (int r = 0; r < 4; r++)
                    zacc[qs][ks][r] += __expf(st[r] * 0.03125f);
            }
    }
    #pragma unroll
    for (int qs = 0; qs < 4; qs++)
        #pragma unroll
        for (int ks = 0; ks < 2; ks++) {
            union { ushort u[4]; uint2v v; } pk;
            #pragma unroll
            for (int r = 0; r < 4; r++)
                pk.u[r] = f2hf(__logf(zacc[qs][ks][r]));
            *(uint2v*)(Zln + (size_t)(b * 2048 + q0 + qs * 16 + li) * 2048 +
                       k0 + wid * 32 + ks * 16 + g * 4) = pk.v;
        }
}

// ------------------- 5. pv: w = exp(st/32 - lnZ), O += w@V -----------------
// 512 blocks (XCD-chunked (qt,b), hp fastest), 256 thr = 4 waves. Wave =
// 32q x 1 head, fully autonomous: private dbuf LDS (K 4KB + V 4KB + Z 2KB
// per buf), 10 gload16/iter, vmcnt(10) counted pipeline, ZERO barriers.
__global__ __launch_bounds__(256, 2) void pv_kernel(
    const ushort* __restrict__ Qb, const ushort* __restrict__ Kb,
    const ushort* __restrict__ Vt, const ushort* __restrict__ Zln,
    ushort* __restrict__ Ob) {
    // per wave, per buf: [K 2048u | V 2048u | Z 1024u] = 5120 ushorts (10KB)
    __shared__ ushort S[4][2][5120];  // 80 KB total
    int tid = threadIdx.x, lane = tid & 63, wv = tid >> 6;  // wave = head
    int li = lane & 15, g = lane >> 4;
    int bid = blockIdx.x;
    int swz = (bid & 7) * 64 + (bid >> 3);
    int hp = swz & 3, p = swz >> 2;        // p in 0..127
    int b = p >> 6, qt = p & 63;
    int q0 = qt * 32;
    int head = hp * 4 + wv;
    // Q fragments in registers (one-time gather)
    short8 qf[2][2];
    #pragma unroll
    for (int qs = 0; qs < 2; qs++)
        #pragma unroll
        for (int dc = 0; dc < 2; dc++)
            qf[qs][dc] = *(const short8*)(
                Qb + (size_t)(b * 2048 + q0 + qs * 16 + li) * 1024 +
                head * 64 + dc * 32 + g * 8);
    f32x4 oacc[2][4] = {};
    // per-lane staging sources (source-swizzled, linear LDS dest)
    const ushort* Ksrc[4];
    const ushort* Vsrc[4];
    const ushort* Zsrc[2];
    #pragma unroll
    for (int i = 0; i < 4; i++) {
        int c = lane + i * 64;
        int kr = c >> 3, km = c & 7;
        Ksrc[i] = Kb + (size_t)(b * 2048 + kr) * 1024 + head * 64 + (km ^ (kr & 7)) * 8;
        int vr = c >> 2, vm = c & 3;
        Vsrc[i] = Vt + (size_t)(b * 1024 + head * 64 + vr) * 2048 + (vm ^ ((vr >> 1) & 3)) * 8;
    }
    #pragma unroll
    for (int i = 0; i < 2; i++) {
        int c = lane + i * 64;
        int zr = c >> 2, zm = c & 3;
        Zsrc[i] = Zln + (size_t)(b * 2048 + q0 + zr) * 2048 + (zm ^ ((zr >> 1) & 3)) * 8;
    }
    #define PV_STAGE(BUF, KB)                                                  \
        {                                                                      \
            ushort* dst = S[wv][BUF];                                          \
            _Pragma("unroll") for (int i = 0; i < 4; i++)                      \
                gload16(Ksrc[i] + (size_t)(KB) * 1024, dst + (lane + i * 64) * 8); \
            _Pragma("unroll") for (int i = 0; i < 4; i++)                      \
                gload16(Vsrc[i] + (KB), dst + 2048 + (lane + i * 64) * 8);     \
            _Pragma("unroll") for (int i = 0; i < 2; i++)                      \
                gload16(Zsrc[i] + (KB), dst + 4096 + (lane + i * 64) * 8);     \
        }
    PV_STAGE(0, 0)
    for (int it = 0; it < 64; ++it) {
        int cur = it & 1;
        int kb = it * 32;
        if (it + 1 < 64) {
            PV_STAGE(cur ^ 1, kb + 32)
            VMCNT(10);
        } else {
            VMCNT(0);
        }
        SCHEDBAR();
        const char* Wb = (const char*)S[wv][cur];
        // ---- QK^T ----
        short8 kf[2][2];
        #pragma unroll
        for (int ks = 0; ks < 2; ks++)
            #pragma unroll
            for (int dc = 0; dc < 2; dc++) {
                int rk = ks * 16 + li;
                kf[ks][dc] = *(const short8*)(
                    Wb + rk * 128 + ((dc * 64 + g * 16) ^ ((rk & 7) << 4)));
            }
        short4v pf[2][2];  // [qs][ks]
        #pragma unroll
        for (int qs = 0; qs < 2; qs++)
            #pragma unroll
            for (int ks = 0; ks < 2; ks++) {
                f32x4 st = {0.f, 0.f, 0.f, 0.f};
                st = MFMA32(kf[ks][0], qf[qs][0], st);
                st = MFMA32(kf[ks][1], qf[qs][1], st);
                int sl = ks * 4 + g;
                int rq = qs * 16 + li;
                union { ushort u[4]; uint2v v; } rz;
                rz.v = *(const uint2v*)(
                    Wb + 8192 + rq * 64 +
                    (((sl >> 1) ^ ((rq >> 1) & 3)) * 2 + (sl & 1)) * 8);
                float e0 = __expf(__builtin_fmaf(st[0], 0.03125f, -hf2f(rz.u[0])));
                float e1 = __expf(__builtin_fmaf(st[1], 0.03125f, -hf2f(rz.u[1])));
                float e2 = __expf(__builtin_fmaf(st[2], 0.03125f, -hf2f(rz.u[2])));
                float e3 = __expf(__builtin_fmaf(st[3], 0.03125f, -hf2f(rz.u[3])));
                unsigned a0 = __float_as_uint(e0) + 0x8000u;
                unsigned a1 = __float_as_uint(e1) + 0x8000u;
                unsigned a2 = __float_as_uint(e2) + 0x8000u;
                unsigned a3 = __float_as_uint(e3) + 0x8000u;
                union { unsigned u[2]; short4v s; } pk;
                pk.u[0] = __builtin_amdgcn_perm(a1, a0, 0x07060302u);
                pk.u[1] = __builtin_amdgcn_perm(a3, a2, 0x07060302u);
                pf[qs][ks] = pk.s;
            }
        // ---- PV ----
        #pragma unroll
        for (int ks = 0; ks < 2; ks++) {
            int sl = ks * 4 + g;
            #pragma unroll
            for (int ds = 0; ds < 4; ds++) {
                int rv = ds * 16 + li;
                short4v vf = *(const short4v*)(
                    Wb + 4096 + rv * 64 +
                    (((sl >> 1) ^ ((rv >> 1) & 3)) * 2 + (sl & 1)) * 8);
                oacc[0][ds] = MFMA16(pf[0][ks], vf, oacc[0][ds]);
                oacc[1][ds] = MFMA16(pf[1][ks], vf, oacc[1][ds]);
            }
        }
    }
    #undef PV_STAGE
    ushort* Oo = Ob + (size_t)(b * 2048 + q0) * 1024 + head * 64;
    #pragma unroll
    for (int qs = 0; qs < 2; qs++)
        #pragma unroll
        for (int ds = 0; ds < 4; ds++)
            #pragma unroll
            for (int r = 0; r < 4; r++)
                Oo[(size_t)(qs * 16 + g * 4 + r) * 1024 + ds * 16 + li] =
                    f2bf(oacc[qs][ds][r]);
}

// ---------------------------------------------------------------------------
extern "C" void kernel_launch(void* const* d_in, const int* in_sizes, int n_in,
                              void* d_out, int out_size, void* d_ws, size_t ws_size,
                              hipStream_t stream) {
    const float* queries = (const float*)d_in[0];
    const float* keys    = (const float*)d_in[1];
    const float* values  = (const float*)d_in[2];
    const float* Wq = (const float*)d_in[3];
    const float* bq = (const float*)d_in[4];
    const float* Wk = (const float*)d_in[5];
    const float* bk = (const float*)d_in[6];
    const float* Wv = (const float*)d_in[7];
    const float* bv = (const float*)d_in[8];
    const float* Wo = (const float*)d_in[9];
    const float* bo = (const float*)d_in[10];
    float* out = (float*)d_out;

    // ws layout (ushort units). Requires ws_size >= 56 MB.
    ushort* Xb  = (ushort*)d_ws;            // [3][4096][1024]   (12M u)
    ushort* Wt  = Xb + 12ull * 1024 * 1024; // [4][1024][1024]   (4M u)
    ushort* Qb  = Wt + 4ull * 1024 * 1024;  // [4096][1024]      (4M u)
    ushort* Kb  = Qb + 4ull * 1024 * 1024;  // [4096][1024]      (4M u)
    ushort* Vtb = Kb + 4ull * 1024 * 1024;  // [2][1024][2048]   (4M u)
    // After projections Xb is dead: Zln (8M u) and Ob (4M u) alias it.
    ushort* Zln = Xb;                        // [2][2048][2048] f16 (8M u)
    ushort* Ob  = Xb + 8ull * 1024 * 1024;   // [4096][1024]        (4M u)

    prep_kernel<<<3072, 256, 0, stream>>>(queries, keys, values, Xb,
                                          Wq, Wk, Wv, Wo, Wt);
    proj_kernel<<<dim3(8, 32, 3), 256, 0, stream>>>(Xb, Wt, bq, bk, bv, Qb, Kb, Vtb);
    zsum_kernel<<<1024, 256, 0, stream>>>(Qb, Kb, Zln);
    pv_kernel<<<512, 256, 0, stream>>>(Qb, Kb, Vtb, Zln, Ob);
    outproj_kernel<<<dim3(8, 32), 256, 0, stream>>>(Ob, Wt + 3ull * 1024 * 1024, bo, out);
}